// Round 1
// 1670.116 us; speedup vs baseline: 10.1594x; 10.1594x over previous
//
#include <hip/hip_runtime.h>

// MLPDecoder_Causal: B=8,N=32,T=32,D=4,K=2,H=256,P=4,E=992.
// R6: latency fix. R5 post-mortem: VALUBusy=4.9%, HBM=0.2% -> pure exposed
// load latency from per-element runtime dtype dispatch (inV F-select) on
// L2-resident weights. This round:
//  - k_prep converts ALL weights + edge softmax to an fp32 ws cache (1.06MB)
//    so k_step is branch-free fp32 with float4 loads.
//  - layer2 register-tiled: thread (rg=tid&7, cg=tid>>3) owns 4 rows x 8 cols;
//    waves PARTITION W2 columns (4x less L2 traffic than rg=tid>>5 mapping).
//  - h1 LDS padded to pitch 260: ds_read_b128 of h1 rows is bank-conflict-free.
//  - aggregation via __shfl_xor butterfly over rg (replaces LDS atomics).
// ws use: 64KB last ping-pong + 1.06MB weight cache.
typedef unsigned short u16;
typedef unsigned int   u32;
typedef unsigned long long u64;

__device__ __forceinline__ float bf2f(u16 s){ u32 u = ((u32)s)<<16; float f; __builtin_memcpy(&f,&u,4); return f; }
// generic input accessor (prep only): F=1 -> memory is bf16 (u16), F=0 -> fp32
__device__ __forceinline__ float inV(const void* p, int i, int F){
  return F ? bf2f(((const u16*)p)[i]) : ((const float*)p)[i];
}

// wave0 scans first 512 u16 of `inputs`: bf16 N(0,1) data never has exponent
// field >= 0xA0 (|x|>=2^33); fp32 low-halves hit that ~37% of the time.
__device__ __forceinline__ void detect_bf16(const void* inputs0, int tid, int* flagL){
  if (tid < 64){
    const uint4* dp = (const uint4*)inputs0;
    uint4 v = dp[tid];
    u32 wds[4] = {v.x, v.y, v.z, v.w};
    int sus = 0;
#pragma unroll
    for (int i2=0; i2<4; ++i2){
      u32 wv = wds[i2];
      u32 h0 = wv & 0xffffu, h1 = wv >> 16;
      if (((h0>>7)&0xffu) >= 0xA0u) sus = 1;
      if (((h1>>7)&0xffu) >= 0xA0u) sus = 1;
    }
    u64 bal = __ballot(sus);
    if (tid == 0) *flagL = (bal == 0ull) ? 1 : 0;
  }
}

// ---------------- workspace layout ----------------
#define WS_LAST0  0
#define WS_LAST1  32768
#define WS_WF     65536      // fp32 weight cache starts here (byte offset)

// offsets in floats within wf
#define WF_W1   0            // [k][kd][c]   2*8*256
#define WF_B1   4096         // [k][c]       2*256
#define WF_W2   4608         // [k][jj][c]   2*256*256
#define WF_B2   135680       // 2*256
#define WF_WO1  136192       // [i][c]       260*256
#define WF_BO1  202752       // 256
#define WF_WO2  203008       // 256*256
#define WF_BO2  268544       // 256
#define WF_WO3  268800       // [i][d]       256*4
#define WF_BO3  269824       // 4
#define WF_EV   269828       // [e][k]       992*2 softmax probs
#define PREP_TOTAL (269828 + 992 + 8192 + 15872)   // = 294884 -> 1152 blocks

// ---------------- prep: dtype-resolve everything once ----------------
__global__ void k_prep(const void* __restrict__ inputs, const void* __restrict__ rel_graph,
                       const void* __restrict__ gumbel,
                       const void* __restrict__ W1, const void* __restrict__ b1,
                       const void* __restrict__ W2, const void* __restrict__ b2,
                       const void* __restrict__ Wo1, const void* __restrict__ bo1,
                       const void* __restrict__ Wo2, const void* __restrict__ bo2,
                       const void* __restrict__ Wo3, const void* __restrict__ bo3,
                       float* __restrict__ wf, float* __restrict__ last0, float* __restrict__ out)
{
  __shared__ int flagL;
  int tid = threadIdx.x;
  detect_bf16(inputs, tid, &flagL);
  __syncthreads();
  const int F = flagL;
  int i = blockIdx.x*256 + tid;
  if (i < WF_EV){                      // weight conversion, flat index == wf index
    const void* src; int off;
    if      (i < WF_B1) { src = W1;  off = i; }
    else if (i < WF_W2) { src = b1;  off = i-WF_B1; }
    else if (i < WF_B2) { src = W2;  off = i-WF_W2; }
    else if (i < WF_WO1){ src = b2;  off = i-WF_B2; }
    else if (i < WF_BO1){ src = Wo1; off = i-WF_WO1; }
    else if (i < WF_WO2){ src = bo1; off = i-WF_BO1; }
    else if (i < WF_BO2){ src = Wo2; off = i-WF_WO2; }
    else if (i < WF_WO3){ src = bo2; off = i-WF_BO2; }
    else if (i < WF_BO3){ src = Wo3; off = i-WF_WO3; }
    else                { src = bo3; off = i-WF_BO3; }
    wf[i] = inV(src, off, F);
    return;
  }
  i -= WF_EV;
  if (i < 992){                        // softmax((rel+gumbel)/0.5), K=2
    float l0 = (inV(rel_graph,2*i,F)   + inV(gumbel,2*i,F))   * 2.f;
    float l1 = (inV(rel_graph,2*i+1,F) + inV(gumbel,2*i+1,F)) * 2.f;
    float m = fmaxf(l0,l1);
    float e0 = __expf(l0-m), e1 = __expf(l1-m), s = 1.f/(e0+e1);
    wf[WF_EV+2*i]   = e0*s;
    wf[WF_EV+2*i+1] = e1*s;
    return;
  }
  i -= 992;
  if (i < 8192){                       // last0[bt][n][d] = inputs[b, n, 4*tp, d]
    int d = i&3, n = (i>>2)&31, bt = i>>7, b = bt>>3, tp = bt&7;
    last0[i] = inV(inputs, b*4096 + n*128 + tp*16 + d, F);
    return;
  }
  i -= 8192;
  if (i < 15872) out[31744 + i] = inV(rel_graph, i % 1984, F);   // rel_out bcast
}

// ---------------- per-step kernel: block = (bt, receiver n) ----------------
#define H1P 260   // h1 LDS pitch: 260%32==4 -> b128 reads of 8 rows hit all 32 banks

__device__ __forceinline__ void fma4(float4& a, float s, float4 w){
  a.x += s*w.x; a.y += s*w.y; a.z += s*w.z; a.w += s*w.w;
}
__device__ __forceinline__ void add4(float4& a, float4 b){
  a.x += b.x; a.y += b.y; a.z += b.z; a.w += b.w;
}
__device__ __forceinline__ float4 relu4(float4 a){
  return make_float4(fmaxf(a.x,0.f), fmaxf(a.y,0.f), fmaxf(a.z,0.f), fmaxf(a.w,0.f));
}

// thread (rg=tid&7, cg=tid>>3): rows j in {rg, rg+8, rg+16, rg+24} (j==31 is a
// masked pad row), cols c = cg*8..cg*8+7. Waves partition the 256 columns.
__global__ __launch_bounds__(256, 4) void k_step(
    const float* __restrict__ lastIn, float* __restrict__ lastOut,
    const float* __restrict__ wf,
    float* __restrict__ hooks, float* __restrict__ out0, int pstep)
{
  __shared__ float xj[32][8];      // [send(4) | recv(4)]; row 31 = zero pad
  __shared__ float evL[31][2];
  __shared__ float h1all[32][H1P];
  __shared__ float augS[260];
  __shared__ float o1L[256];
  __shared__ float o2L[256];

  const int tid = threadIdx.x;
  const int n = blockIdx.x & 31, bt = blockIdx.x >> 5;
  const int b = bt>>3, tp = bt&7;
  const int rg = tid & 7, cgi = tid >> 3;
  const int c = cgi*8;

  if (tid < 32){                   // xj staging from fp32 ws
    int j = tid;
    float4 sv = make_float4(0.f,0.f,0.f,0.f), rv = sv;
    if (j < 31){
      int s = j + (j >= n);
      sv = *(const float4*)&lastIn[bt*128 + s*4];
      rv = *(const float4*)&lastIn[bt*128 + n*4];
    }
    *(float4*)&xj[j][0] = sv;
    *(float4*)&xj[j][4] = rv;
  } else if (tid < 63){            // precomputed edge softmax from ws
    int j = tid - 32, e = n*31 + j;
    evL[j][0] = wf[WF_EV + 2*e];
    evL[j][1] = wf[WF_EV + 2*e + 1];
  }
  __syncthreads();

  float4 agg0 = make_float4(0.f,0.f,0.f,0.f), agg1 = agg0;

  for (int k=0; k<2; ++k){
    // ---- layer1 into registers: h1 = relu(x @ W1[k] + b1[k])
    float4 a0[4], a1[4];
    {
      float4 bb0 = *(const float4*)&wf[WF_B1 + k*256 + c];
      float4 bb1 = *(const float4*)&wf[WF_B1 + k*256 + c + 4];
#pragma unroll
      for (int ri=0; ri<4; ++ri){ a0[ri] = bb0; a1[ri] = bb1; }
      const float* W1k = wf + WF_W1 + k*2048;
#pragma unroll
      for (int kd=0; kd<8; ++kd){
        float4 w0 = *(const float4*)&W1k[kd*256 + c];
        float4 w1 = *(const float4*)&W1k[kd*256 + c + 4];
#pragma unroll
        for (int ri=0; ri<4; ++ri){
          float xv = xj[rg + 8*ri][kd];
          fma4(a0[ri], xv, w0); fma4(a1[ri], xv, w1);
        }
      }
    }
    if (k) __syncthreads();        // all k=0 h1 reads done before overwrite
#pragma unroll
    for (int ri=0; ri<4; ++ri){
      int j = rg + 8*ri;
      *(float4*)&h1all[j][c]     = relu4(a0[ri]);
      *(float4*)&h1all[j][c + 4] = relu4(a1[ri]);
    }
    __syncthreads();               // h1all ready

    // ---- layer2: h2 = relu(h1 @ W2[k] + b2[k]); 4x8 register tile
    float4 acc0[4], acc1[4];
    {
      float4 b20 = *(const float4*)&wf[WF_B2 + k*256 + c];
      float4 b21 = *(const float4*)&wf[WF_B2 + k*256 + c + 4];
#pragma unroll
      for (int ri=0; ri<4; ++ri){ acc0[ri] = b20; acc1[ri] = b21; }
    }
    const float* W2k = wf + WF_W2 + k*65536;
    for (int jj=0; jj<256; jj+=4){
      float4 w0[4], w1[4];
#pragma unroll
      for (int u=0; u<4; ++u){
        w0[u] = *(const float4*)&W2k[(jj+u)*256 + c];
        w1[u] = *(const float4*)&W2k[(jj+u)*256 + c + 4];
      }
#pragma unroll
      for (int ri=0; ri<4; ++ri){
        float4 hv = *(const float4*)&h1all[rg + 8*ri][jj];   // conflict-free b128
        fma4(acc0[ri], hv.x, w0[0]); fma4(acc0[ri], hv.y, w0[1]);
        fma4(acc0[ri], hv.z, w0[2]); fma4(acc0[ri], hv.w, w0[3]);
        fma4(acc1[ri], hv.x, w1[0]); fma4(acc1[ri], hv.y, w1[1]);
        fma4(acc1[ri], hv.z, w1[2]); fma4(acc1[ri], hv.w, w1[3]);
      }
    }

    // ---- edge scale, hooks (k=1), per-thread column partial sums
#pragma unroll
    for (int ri=0; ri<4; ++ri){
      int j = rg + 8*ri;
      if (j < 31){
        float ev = evL[j][k];
        float4 m0 = relu4(acc0[ri]); m0.x*=ev; m0.y*=ev; m0.z*=ev; m0.w*=ev;
        float4 m1 = relu4(acc1[ri]); m1.x*=ev; m1.y*=ev; m1.z*=ev; m1.w*=ev;
        if (k == 1){
          int hb = (((pstep*8 + tp)*8 + b)*992 + n*31 + j)*256 + c;
          *(float4*)&hooks[hb]     = m0;
          *(float4*)&hooks[hb + 4] = m1;
        }
        add4(agg0, m0); add4(agg1, m1);
      }
    }
  }

  // ---- aggregate over rows: butterfly across rg lanes (tid&7), no atomics
#pragma unroll
  for (int m=1; m<8; m<<=1){
    agg0.x += __shfl_xor(agg0.x, m); agg0.y += __shfl_xor(agg0.y, m);
    agg0.z += __shfl_xor(agg0.z, m); agg0.w += __shfl_xor(agg0.w, m);
    agg1.x += __shfl_xor(agg1.x, m); agg1.y += __shfl_xor(agg1.y, m);
    agg1.z += __shfl_xor(agg1.z, m); agg1.w += __shfl_xor(agg1.w, m);
  }
  if (rg == 0){
    *(float4*)&augS[4 + c]     = agg0;
    *(float4*)&augS[4 + c + 4] = agg1;
  }
  if (tid < 4) augS[tid] = lastIn[bt*128 + n*4 + tid];
  __syncthreads();

  // ---- output MLP: aug(260) -> Wo1 relu -> Wo2 relu -> Wo3 + residual
  {
    float a = wf[WF_BO1 + tid];
    const float* Wp = wf + WF_WO1 + tid;
#pragma unroll 4
    for (int i=0; i<260; ++i) a += augS[i]*Wp[i*256];
    o1L[tid] = fmaxf(a, 0.f);
  }
  __syncthreads();
  {
    float a = wf[WF_BO2 + tid];
    const float* Wp = wf + WF_WO2 + tid;
#pragma unroll 8
    for (int i=0; i<256; ++i) a += o1L[i]*Wp[i*256];
    o2L[tid] = fmaxf(a, 0.f);
  }
  __syncthreads();
  if (tid < 64){
    int d = tid & 3, ch = tid >> 2;        // 16 chunks x 16 elems
    float p = 0.f;
#pragma unroll
    for (int ii=0; ii<16; ++ii){
      int i = ch*16 + ii;
      p += o2L[i]*wf[WF_WO3 + i*4 + d];
    }
#pragma unroll
    for (int s=4; s<64; s<<=1) p += __shfl_xor(p, s);
    if (ch == 0){
      float lv = lastIn[bt*128 + n*4 + d] + p + wf[WF_BO3 + d];
      lastOut[bt*128 + n*4 + d] = lv;
      int t = tp*4 + pstep;
      if (t < 31) out0[b*3968 + n*124 + t*4 + d] = lv;
    }
  }
}

extern "C" void kernel_launch(void* const* d_in, const int* in_sizes, int n_in,
                              void* d_out, int out_size, void* d_ws, size_t ws_size,
                              hipStream_t stream) {
  const void* inputs    = d_in[0];
  const void* rel_graph = d_in[1];
  const void* W1  = d_in[2];
  const void* b1  = d_in[3];
  const void* W2  = d_in[4];
  const void* b2  = d_in[5];
  const void* Wo1 = d_in[6];
  const void* bo1 = d_in[7];
  const void* Wo2 = d_in[8];
  const void* bo2 = d_in[9];
  const void* Wo3 = d_in[10];
  const void* bo3 = d_in[11];
  const void* gumbel = d_in[14];
  float* out = (float*)d_out;
  char* ws = (char*)d_ws;
  float* L0 = (float*)(ws + WS_LAST0);
  float* L1 = (float*)(ws + WS_LAST1);
  float* wf = (float*)(ws + WS_WF);

  k_prep<<<(PREP_TOTAL + 255)/256, 256, 0, stream>>>(
      inputs, rel_graph, gumbel, W1, b1, W2, b2, Wo1, bo1, Wo2, bo2, Wo3, bo3,
      wf, L0, out);
  for (int p = 0; p < 4; ++p) {
    const float* lin  = (p & 1) ? L1 : L0;
    float*       lout = (p & 1) ? L0 : L1;
    k_step<<<2048, 256, 0, stream>>>(lin, lout, wf, out + 47616, out, p);
  }
}

// Round 2
// 664.413 us; speedup vs baseline: 25.5375x; 2.5137x over previous
//
#include <hip/hip_runtime.h>

// MLPDecoder_Causal: B=8,N=32,T=32,D=4,K=2,H=256,P=4,E=992.
// R7: layer2 -> MFMA (split-precision bf16hi+lo, 3 products => ~fp32 accuracy).
// R6 post-mortem: VALUBusy 80%, MfmaUtil 0 -> GEMM on the vector pipe; fp32
// VALU roofline for layer2 alone is ~424us/step-dispatch. This round:
//  - k_prep packs W2 into MFMA fragment order as bf16 {hi,lo} (512KB ws).
//  - k_msg: h1 fp32 on VALU (tiny), split->bf16 frags in LDS (lane-linear),
//    layer2 = 16x16x32 bf16 MFMA, M=32 edges x N=256 x K=256, acc init = b2.
//    Epilogue relu*ev, hooks stores, agg via shfl reduce -> ws.
//  - k_out: output MLP as 256-block x 8-row batched GEMM (Wo1/Wo2 traffic /8;
//    R6 re-read 522KB per block x 2048 blocks = 1.07GB/dispatch from L2).
// ws: 64KB last ping-pong + 563KB wf + 512KB W2pack + 2MB agg (~3.2MB).
typedef unsigned short u16;
typedef unsigned int   u32;
typedef unsigned long long u64;
typedef __attribute__((ext_vector_type(8))) short bf16x8;   // 8 bf16 (4 VGPR)
typedef __attribute__((ext_vector_type(4))) float f32x4;

__device__ __forceinline__ float bf2f(u16 s){ u32 u = ((u32)s)<<16; float f; __builtin_memcpy(&f,&u,4); return f; }
__device__ __forceinline__ u16 f2bf(float f){            // RNE fp32->bf16
  u32 u; __builtin_memcpy(&u,&f,4);
  u32 r = u + 0x7fffu + ((u>>16)&1u);
  return (u16)(r>>16);
}
// generic input accessor (prep only): F=1 -> memory is bf16, F=0 -> fp32
__device__ __forceinline__ float inV(const void* p, int i, int F){
  return F ? bf2f(((const u16*)p)[i]) : ((const float*)p)[i];
}

// wave0 scans first 512 u16 of `inputs`: bf16 N(0,1) data never has exponent
// field >= 0xA0; fp32 low-halves hit that ~37% of the time.
__device__ __forceinline__ void detect_bf16(const void* inputs0, int tid, int* flagL){
  if (tid < 64){
    const uint4* dp = (const uint4*)inputs0;
    uint4 v = dp[tid];
    u32 wds[4] = {v.x, v.y, v.z, v.w};
    int sus = 0;
#pragma unroll
    for (int i2=0; i2<4; ++i2){
      u32 wv = wds[i2];
      u32 h0 = wv & 0xffffu, h1 = wv >> 16;
      if (((h0>>7)&0xffu) >= 0xA0u) sus = 1;
      if (((h1>>7)&0xffu) >= 0xA0u) sus = 1;
    }
    u64 bal = __ballot(sus);
    if (tid == 0) *flagL = (bal == 0ull) ? 1 : 0;
  }
}

// ---------------- workspace layout (bytes) ----------------
#define WS_LAST0 0
#define WS_LAST1 32768
#define WS_WF    65536       // fp32 misc weights, 140740 floats
#define WS_W2P   720896      // W2 bf16 fragment pack, 262144 u16 = 512KB
#define WS_AGG   1245184     // agg [2048][256] f32 = 2MB

// wf offsets (floats)
#define WF_W1   0            // [k][kd][c]  2*8*256
#define WF_B1   4096         // 2*256
#define WF_B2   4608         // 2*256
#define WF_WO1  5120         // [i][c] 260*256
#define WF_BO1  71680        // 256
#define WF_WO2  71936        // 256*256
#define WF_BO2  137472       // 256
#define WF_WO3  137728       // [i][d] 256*4
#define WF_BO3  138752       // 4
#define WF_EV   138756       // [e][k] 992*2 softmax probs

// prep flat-work partition
#define PR_WF   138756
#define PR_EV   (PR_WF + 992)       // 139748
#define PR_L0   (PR_EV + 8192)      // 147940
#define PR_RO   (PR_L0 + 15872)     // 163812
#define PR_W2P  (PR_RO + 262144)    // 425956

// ---------------- prep: dtype-resolve + pack everything once ----------------
__global__ void k_prep(const void* __restrict__ inputs, const void* __restrict__ rel_graph,
                       const void* __restrict__ gumbel,
                       const void* __restrict__ W1, const void* __restrict__ b1,
                       const void* __restrict__ W2, const void* __restrict__ b2,
                       const void* __restrict__ Wo1, const void* __restrict__ bo1,
                       const void* __restrict__ Wo2, const void* __restrict__ bo2,
                       const void* __restrict__ Wo3, const void* __restrict__ bo3,
                       float* __restrict__ wf, u16* __restrict__ w2p,
                       float* __restrict__ last0, float* __restrict__ out)
{
  __shared__ int flagL;
  int tid = threadIdx.x;
  detect_bf16(inputs, tid, &flagL);
  __syncthreads();
  const int F = flagL;
  int i = blockIdx.x*256 + tid;
  if (i < PR_WF){                      // fp32 weight cache, flat index == wf index
    const void* src; int off;
    if      (i < 4096)   { src = W1;  off = i; }
    else if (i < 4608)   { src = b1;  off = i-4096; }
    else if (i < 5120)   { src = b2;  off = i-4608; }
    else if (i < 71680)  { src = Wo1; off = i-5120; }
    else if (i < 71936)  { src = bo1; off = i-71680; }
    else if (i < 137472) { src = Wo2; off = i-71936; }
    else if (i < 137728) { src = bo2; off = i-137472; }
    else if (i < 138752) { src = Wo3; off = i-137728; }
    else                 { src = bo3; off = i-138752; }
    wf[i] = inV(src, off, F);
    return;
  }
  if (i < PR_EV){                      // softmax((rel+gumbel)/0.5), K=2
    int e = i - PR_WF;
    float l0 = (inV(rel_graph,2*e,F)   + inV(gumbel,2*e,F))   * 2.f;
    float l1 = (inV(rel_graph,2*e+1,F) + inV(gumbel,2*e+1,F)) * 2.f;
    float m = fmaxf(l0,l1);
    float e0 = __expf(l0-m), e1 = __expf(l1-m), s = 1.f/(e0+e1);
    wf[WF_EV+2*e]   = e0*s;
    wf[WF_EV+2*e+1] = e1*s;
    return;
  }
  if (i < PR_L0){                      // last0[bt][n][d] = inputs[b, n, 4*tp, d]
    int j = i - PR_EV;
    int d = j&3, n = (j>>2)&31, bt = j>>7, b = bt>>3, tp = bt&7;
    last0[j] = inV(inputs, b*4096 + n*128 + tp*16 + d, F);
    return;
  }
  if (i < PR_RO){                      // rel_out broadcast
    int j = i - PR_L0;
    out[31744 + j] = inV(rel_graph, j % 1984, F);
    return;
  }
  if (i < PR_W2P){                     // W2 -> bf16 {hi,lo} fragment pack
    // flat: ((((k*2+part)*16 + t)*8 + q)*64 + l)*8 + ei
    int e = i - PR_RO;
    int ei = e & 7, l = (e>>3)&63, q = (e>>9)&7, t = (e>>12)&15,
        part = (e>>16)&1, k = e>>17;
    int kk  = q*32 + (l>>4)*8 + ei;    // contraction index (h1 col)
    int col = t*16 + (l&15);           // output col
    float f = inV(W2, k*65536 + kk*256 + col, F);
    u16 h = f2bf(f);
    w2p[e] = part ? f2bf(f - bf2f(h)) : h;
  }
}

// ---------------- k_msg: edge MLP (layer1 VALU, layer2 MFMA) ----------------
__device__ __forceinline__ void fma4(float4& a, float s, float4 w){
  a.x += s*w.x; a.y += s*w.y; a.z += s*w.z; a.w += s*w.w;
}

// block = (bt, receiver n). 4 waves partition the 256 output cols (64 each).
// A-frags (h1 hi/lo) in LDS, lane-linear: frag[rt*8+q][lane] holds
// row m=(lane&15)+16*rt, k = q*32 + (lane>>4)*8 + i  (i=0..7 contiguous).
__global__ __launch_bounds__(256) void k_msg(
    const float* __restrict__ lastIn, const float* __restrict__ wf,
    const u16* __restrict__ w2p, float* __restrict__ agg,
    float* __restrict__ hooks, int pstep)
{
  __shared__ float xj[32][8];      // [send(4) | recv(4)]; row 31 = zero pad
  __shared__ float evL[31][2];
  __shared__ uint4 AhF[16][64];    // h1 hi frags, 16KB
  __shared__ uint4 AlF[16][64];    // h1 lo frags, 16KB

  const int tid = threadIdx.x;
  const int n = blockIdx.x & 31, bt = blockIdx.x >> 5;
  const int b = bt>>3, tp = bt&7;
  const int rg = tid & 7, cgi = tid >> 3, c = cgi*8;
  const int lane = tid & 63, wave = tid >> 6;
  const int l15 = lane & 15, lg = lane >> 4;

  if (tid < 32){                   // xj staging
    int j = tid;
    float4 sv = make_float4(0.f,0.f,0.f,0.f), rv = sv;
    if (j < 31){
      int s = j + (j >= n);
      sv = *(const float4*)&lastIn[bt*128 + s*4];
      rv = *(const float4*)&lastIn[bt*128 + n*4];
    }
    *(float4*)&xj[j][0] = sv;
    *(float4*)&xj[j][4] = rv;
  } else if (tid < 63){            // precomputed edge softmax
    int j = tid - 32, e = n*31 + j;
    evL[j][0] = wf[WF_EV + 2*e];
    evL[j][1] = wf[WF_EV + 2*e + 1];
  }
  __syncthreads();

  const int hb = (((pstep*8 + tp)*8 + b)*992 + n*31)*256;
  float aggl[4] = {0.f,0.f,0.f,0.f};

  for (int k=0; k<2; ++k){
    // ---- layer1 fp32: h1 = relu(x @ W1[k] + b1[k]); thread = 4 rows x 8 cols
    float4 a0[4], a1[4];
    {
      float4 bb0 = *(const float4*)&wf[WF_B1 + k*256 + c];
      float4 bb1 = *(const float4*)&wf[WF_B1 + k*256 + c + 4];
#pragma unroll
      for (int ri=0; ri<4; ++ri){ a0[ri] = bb0; a1[ri] = bb1; }
      const float* W1k = wf + WF_W1 + k*2048;
#pragma unroll
      for (int kd=0; kd<8; ++kd){
        float4 w0 = *(const float4*)&W1k[kd*256 + c];
        float4 w1 = *(const float4*)&W1k[kd*256 + c + 4];
#pragma unroll
        for (int ri=0; ri<4; ++ri){
          float xv = xj[rg + 8*ri][kd];
          fma4(a0[ri], xv, w0); fma4(a1[ri], xv, w1);
        }
      }
    }
    if (k) __syncthreads();        // all waves done reading k=0 frags
    // ---- split to bf16 hi/lo, store A-frags (writer (j,c) -> frag slot == lane)
#pragma unroll
    for (int ri=0; ri<4; ++ri){
      int j = rg + 8*ri;
      float v[8] = { fmaxf(a0[ri].x,0.f), fmaxf(a0[ri].y,0.f),
                     fmaxf(a0[ri].z,0.f), fmaxf(a0[ri].w,0.f),
                     fmaxf(a1[ri].x,0.f), fmaxf(a1[ri].y,0.f),
                     fmaxf(a1[ri].z,0.f), fmaxf(a1[ri].w,0.f) };
      u32 hw[4], lw[4];
#pragma unroll
      for (int e2=0; e2<4; ++e2){
        u16 h0 = f2bf(v[2*e2]),   h1 = f2bf(v[2*e2+1]);
        u16 g0 = f2bf(v[2*e2]   - bf2f(h0));
        u16 g1 = f2bf(v[2*e2+1] - bf2f(h1));
        hw[e2] = (u32)h0 | ((u32)h1<<16);
        lw[e2] = (u32)g0 | ((u32)g1<<16);
      }
      int fi   = ((j>>4)<<3) + (cgi>>2);        // rt*8 + kchunk
      int slot = (j&15) + ((cgi&3)<<4);
      AhF[fi][slot] = make_uint4(hw[0],hw[1],hw[2],hw[3]);
      AlF[fi][slot] = make_uint4(lw[0],lw[1],lw[2],lw[3]);
    }
    __syncthreads();               // frags ready

    // ---- layer2 MFMA: acc(+b2) += Ah*Bh + Al*Bh + Ah*Bl
    f32x4 acc[2][4];
#pragma unroll
    for (int nt=0; nt<4; ++nt){
      float bv = wf[WF_B2 + k*256 + wave*64 + nt*16 + l15];
      f32x4 t = {bv,bv,bv,bv};
      acc[0][nt] = t; acc[1][nt] = t;
    }
    const u16* W2pk = w2p + k*131072;
#pragma unroll 2
    for (int q=0; q<8; ++q){
      bf16x8 Ah0 = __builtin_bit_cast(bf16x8, AhF[q][lane]);
      bf16x8 Ah1 = __builtin_bit_cast(bf16x8, AhF[8+q][lane]);
      bf16x8 Al0 = __builtin_bit_cast(bf16x8, AlF[q][lane]);
      bf16x8 Al1 = __builtin_bit_cast(bf16x8, AlF[8+q][lane]);
#pragma unroll
      for (int nt=0; nt<4; ++nt){
        int tt = wave*4 + nt;
        const u16* bp = W2pk + ((tt*8 + q)*64 + lane)*8;
        bf16x8 Bh = __builtin_bit_cast(bf16x8, *(const uint4*)bp);
        bf16x8 Bl = __builtin_bit_cast(bf16x8, *(const uint4*)(bp + 65536));
        acc[0][nt] = __builtin_amdgcn_mfma_f32_16x16x32_bf16(Ah0, Bh, acc[0][nt], 0,0,0);
        acc[1][nt] = __builtin_amdgcn_mfma_f32_16x16x32_bf16(Ah1, Bh, acc[1][nt], 0,0,0);
        acc[0][nt] = __builtin_amdgcn_mfma_f32_16x16x32_bf16(Al0, Bh, acc[0][nt], 0,0,0);
        acc[1][nt] = __builtin_amdgcn_mfma_f32_16x16x32_bf16(Al1, Bh, acc[1][nt], 0,0,0);
        acc[0][nt] = __builtin_amdgcn_mfma_f32_16x16x32_bf16(Ah0, Bl, acc[0][nt], 0,0,0);
        acc[1][nt] = __builtin_amdgcn_mfma_f32_16x16x32_bf16(Ah1, Bl, acc[1][nt], 0,0,0);
      }
    }

    // ---- epilogue: relu, edge scale, hooks (k=1), per-lane agg partials
    // D layout (verified): row = lg*4+reg (+16*rt), col = l15 (+16*nt+64*wave)
#pragma unroll
    for (int rt=0; rt<2; ++rt){
#pragma unroll
      for (int r=0; r<4; ++r){
        int j = rt*16 + lg*4 + r;
        if (j < 31){
          float ev = evL[j][k];
#pragma unroll
          for (int nt=0; nt<4; ++nt){
            float m = fmaxf(acc[rt][nt][r], 0.f) * ev;
            aggl[nt] += m;
            if (k == 1) hooks[hb + j*256 + wave*64 + nt*16 + l15] = m;
          }
        }
      }
    }
  }

  // ---- reduce rows across the 4 lane-groups, store agg (64 cols per wave)
#pragma unroll
  for (int nt=0; nt<4; ++nt){
    aggl[nt] += __shfl_xor(aggl[nt], 16);
    aggl[nt] += __shfl_xor(aggl[nt], 32);
  }
  if (lane < 16){
#pragma unroll
    for (int nt=0; nt<4; ++nt)
      agg[blockIdx.x*256 + wave*64 + nt*16 + lane] = aggl[nt];
  }
}

// ---------------- k_out: output MLP, 8 rows/block (weights reused 8x) ----------------
__global__ __launch_bounds__(256) void k_out(
    const float* __restrict__ lastIn, float* __restrict__ lastOut,
    const float* __restrict__ wf, const float* __restrict__ agg,
    float* __restrict__ out0, int pstep)
{
  __shared__ float augT[8][264];
  __shared__ float o1T[8][264];
  __shared__ float o2T[8][264];
  const int tid = threadIdx.x;
  const int r0 = blockIdx.x*8;

#pragma unroll
  for (int rr=0; rr<8; ++rr) augT[rr][4+tid] = agg[(r0+rr)*256 + tid];
  if (tid < 32){
    int rr = tid>>2, d = tid&3, r = r0+rr;
    augT[rr][d] = lastIn[(r>>5)*128 + (r&31)*4 + d];
  }
  __syncthreads();
  {  // o1 = relu(aug @ Wo1 + bo1); thread = col, 8 rows
    float acc[8];
    float bv = wf[WF_BO1 + tid];
#pragma unroll
    for (int rr=0; rr<8; ++rr) acc[rr] = bv;
    for (int i4=0; i4<260; i4+=4){
      float w0 = wf[WF_WO1 + (i4+0)*256 + tid];
      float w1 = wf[WF_WO1 + (i4+1)*256 + tid];
      float w2 = wf[WF_WO1 + (i4+2)*256 + tid];
      float w3 = wf[WF_WO1 + (i4+3)*256 + tid];
#pragma unroll
      for (int rr=0; rr<8; ++rr){
        float4 x = *(const float4*)&augT[rr][i4];
        acc[rr] += x.x*w0 + x.y*w1 + x.z*w2 + x.w*w3;
      }
    }
#pragma unroll
    for (int rr=0; rr<8; ++rr) o1T[rr][tid] = fmaxf(acc[rr], 0.f);
  }
  __syncthreads();
  {  // o2 = relu(o1 @ Wo2 + bo2)
    float acc[8];
    float bv = wf[WF_BO2 + tid];
#pragma unroll
    for (int rr=0; rr<8; ++rr) acc[rr] = bv;
    for (int i4=0; i4<256; i4+=4){
      float w0 = wf[WF_WO2 + (i4+0)*256 + tid];
      float w1 = wf[WF_WO2 + (i4+1)*256 + tid];
      float w2 = wf[WF_WO2 + (i4+2)*256 + tid];
      float w3 = wf[WF_WO2 + (i4+3)*256 + tid];
#pragma unroll
      for (int rr=0; rr<8; ++rr){
        float4 x = *(const float4*)&o1T[rr][i4];
        acc[rr] += x.x*w0 + x.y*w1 + x.z*w2 + x.w*w3;
      }
    }
#pragma unroll
    for (int rr=0; rr<8; ++rr) o2T[rr][tid] = fmaxf(acc[rr], 0.f);
  }
  __syncthreads();
  if (tid < 64){   // p = o2 @ Wo3 + bo3; residual; store
    int d = tid&3, half = (tid>>2)&1, r = tid>>3;
    float p = 0.f;
    for (int ii=0; ii<128; ++ii){
      int i = half*128 + ii;
      p += o2T[r][i]*wf[WF_WO3 + i*4 + d];
    }
    p += __shfl_xor(p, 4);
    if (!half){
      int row = r0 + r, bt = row>>5, nn = row&31;
      float lv = lastIn[bt*128 + nn*4 + d] + p + wf[WF_BO3 + d];
      lastOut[bt*128 + nn*4 + d] = lv;
      int bb = bt>>3, tp = bt&7, t = tp*4 + pstep;
      if (t < 31) out0[bb*3968 + nn*124 + t*4 + d] = lv;
    }
  }
}

extern "C" void kernel_launch(void* const* d_in, const int* in_sizes, int n_in,
                              void* d_out, int out_size, void* d_ws, size_t ws_size,
                              hipStream_t stream) {
  const void* inputs    = d_in[0];
  const void* rel_graph = d_in[1];
  const void* W1  = d_in[2];
  const void* b1  = d_in[3];
  const void* W2  = d_in[4];
  const void* b2  = d_in[5];
  const void* Wo1 = d_in[6];
  const void* bo1 = d_in[7];
  const void* Wo2 = d_in[8];
  const void* bo2 = d_in[9];
  const void* Wo3 = d_in[10];
  const void* bo3 = d_in[11];
  const void* gumbel = d_in[14];
  float* out = (float*)d_out;
  char* ws = (char*)d_ws;
  float* L0   = (float*)(ws + WS_LAST0);
  float* L1   = (float*)(ws + WS_LAST1);
  float* wf   = (float*)(ws + WS_WF);
  u16*   w2p  = (u16*)  (ws + WS_W2P);
  float* aggp = (float*)(ws + WS_AGG);

  k_prep<<<(PR_W2P + 255)/256, 256, 0, stream>>>(
      inputs, rel_graph, gumbel, W1, b1, W2, b2, Wo1, bo1, Wo2, bo2, Wo3, bo3,
      wf, w2p, L0, out);
  for (int p = 0; p < 4; ++p) {
    const float* lin  = (p & 1) ? L1 : L0;
    float*       lout = (p & 1) ? L0 : L1;
    k_msg<<<2048, 256, 0, stream>>>(lin, wf, w2p, aggp, out + 47616, p);
    k_out<<<256, 256, 0, stream>>>(lin, lout, wf, aggp, out, p);
  }
}